// Round 11
// baseline (8988.733 us; speedup 1.0000x reference)
//
#include <hip/hip_runtime.h>
#include <math.h>

#define HH 256
#define FIN 6
#define TT 4096
#define BB 32
#define TH 0.05f

typedef _Float16 half8 __attribute__((ext_vector_type(8)));
typedef float f4 __attribute__((ext_vector_type(4)));

__device__ __forceinline__ float hswish(float v) {
    float c = fminf(fmaxf(v + 3.0f, 0.0f), 6.0f);
    return v * c * (1.0f / 6.0f);
}
__device__ __forceinline__ float fexp2(float x) { return __builtin_amdgcn_exp2f(x); }
__device__ __forceinline__ float frcp(float x)  { return __builtin_amdgcn_rcpf(x); }
__device__ __forceinline__ float sigm(float x)  { return frcp(1.0f + fexp2(-1.44269504f * x)); }
__device__ __forceinline__ float tanhf_fast(float x) {
    float ax = fabsf(x);
    float e = fexp2(2.88539008f * ax);
    float t = 1.0f - 2.0f * frcp(e + 1.0f);
    return copysignf(t, x);
}

// DPP row_shr sum over 16 lanes (VALU pipe); sum lands in lane 15 of each row.
__device__ __forceinline__ float dpp_row_sum16(float p) {
    int x = __float_as_int(p);
    p += __int_as_float(__builtin_amdgcn_update_dpp(0, x, 0x118, 0xF, 0xF, true));
    x = __float_as_int(p);
    p += __int_as_float(__builtin_amdgcn_update_dpp(0, x, 0x114, 0xF, 0xF, true));
    x = __float_as_int(p);
    p += __int_as_float(__builtin_amdgcn_update_dpp(0, x, 0x112, 0xF, 0xF, true));
    x = __float_as_int(p);
    p += __int_as_float(__builtin_amdgcn_update_dpp(0, x, 0x111, 0xF, 0xF, true));
    return p;
}

// Kernel 1: feats (B,T,6) into ws, conv skip path into d_out.
__global__ __launch_bounds__(256) void k_prep(
        const float* __restrict__ x, const float* __restrict__ Wc1,
        const float* __restrict__ Wc2, float* __restrict__ feats,
        float* __restrict__ out) {
    int idx = blockIdx.x * 256 + threadIdx.x;   // b*T + t
    if (idx >= BB * TT) return;
    int b = idx >> 12;
    int t = idx & (TT - 1);
    const float* xb = x + (size_t)b * TT * 2;
    float i0 = xb[t * 2 + 0], q0 = xb[t * 2 + 1];
    float ip = (t > 0) ? xb[(t - 1) * 2 + 0] : 0.0f;
    float qp = (t > 0) ? xb[(t - 1) * 2 + 1] : 0.0f;
    float amp2 = i0 * i0 + q0 * q0;
    float amp  = sqrtf(fmaxf(amp2, 1e-12f));
    float amp3 = amp * amp2;
    float* f = feats + (size_t)idx * 6;
    f[0] = i0; f[1] = q0; f[2] = amp; f[3] = amp3; f[4] = ip; f[5] = qp;

    float c1[3];
#pragma unroll
    for (int m = 0; m < 3; m++) {
        float acc = 0.0f;
#pragma unroll
        for (int k = 0; k < 3; k++) {
            int tt = t + (k - 1) * 16;
            if (tt >= 0 && tt < TT) {
                acc += Wc1[m * 6 + 0 * 3 + k] * xb[tt * 2 + 0];
                acc += Wc1[m * 6 + 1 * 3 + k] * xb[tt * 2 + 1];
            }
        }
        c1[m] = hswish(acc);
    }
#pragma unroll
    for (int o = 0; o < 2; o++) {
        float acc = Wc2[o * 3 + 0] * c1[0] + Wc2[o * 3 + 1] * c1[1] + Wc2[o * 3 + 2] * c1[2];
        out[(size_t)idx * 2 + o] = hswish(acc);
    }
}

// Kernel 1b: pack z and n gates as fp16 MFMA A-fragments.
// Fragment (rt 0..15, kc 0..7, lane 0..63) = 8 halfs:
//   Wh[gate][16*rt + (lane&15)][32*kc + ((lane>>4)&3)*8 + j], j=0..7
// stored linearly at ((rt*8 + kc)*64 + lane)*8.
__global__ __launch_bounds__(256) void k_pack(
        const float* __restrict__ Wh, _Float16* __restrict__ zp,
        _Float16* __restrict__ np) {
    int id = blockIdx.x * 256 + threadIdx.x;     // 0..16383
    if (id >= 16384) return;
    int gi  = id >> 13;                           // 0 = z(gate1), 1 = n(gate2)
    int fid = id & 8191;
    int rt  = fid >> 9;
    int kc  = (fid >> 6) & 7;
    int ln  = fid & 63;
    const float* s = Wh + ((size_t)((1 + gi) * HH + 16 * rt + (ln & 15))) * HH
                   + 32 * kc + ((ln >> 4) & 3) * 8;
    _Float16* d = (gi ? np : zp) + (size_t)fid * 8;
    float4 u = *(const float4*)s;
    float4 v = *(const float4*)(s + 4);
    d[0] = (_Float16)u.x; d[1] = (_Float16)u.y; d[2] = (_Float16)u.z; d[3] = (_Float16)u.w;
    d[4] = (_Float16)v.x; d[5] = (_Float16)v.y; d[6] = (_Float16)v.z; d[7] = (_Float16)v.w;
}

#define MFMA(A, B, C) __builtin_amdgcn_mfma_f32_16x16x32_f16((A), (B), (C), 0, 0, 0)

// reg-select by c (lane bits 0,1), tile-select by b (lane bits 2,3)
#define EXTRACT(C0, C1, C2, C3, DST) {                                         \
    float e0_ = c2 ? (c1 ? C0[3] : C0[2]) : (c1 ? C0[1] : C0[0]);              \
    float e1_ = c2 ? (c1 ? C1[3] : C1[2]) : (c1 ? C1[1] : C1[0]);              \
    float e2_ = c2 ? (c1 ? C2[3] : C2[2]) : (c1 ? C2[1] : C2[0]);              \
    float e3_ = c2 ? (c1 ? C3[3] : C3[2]) : (c1 ? C3[1] : C3[0]);              \
    float u0_ = b1t ? e1_ : e0_;                                               \
    float u1_ = b1t ? e3_ : e2_;                                               \
    DST = b2t ? u1_ : u0_; }

#define RS(KC) {                                                               \
    half8 bf = *(const half8*)(dhb + 32 * (KC) + a_ * 8);                      \
    cr0 = MFMA(ar[0][KC], bf, cr0); cr1 = MFMA(ar[1][KC], bf, cr1);            \
    cr2 = MFMA(ar[2][KC], bf, cr2); cr3 = MFMA(ar[3][KC], bf, cr3); }

#define ZN(KC, N0, N1, N2, N3) {                                               \
    half8 bf = *(const half8*)(dhb + 32 * (KC) + a_ * 8);                      \
    half8 z0 = zlb[o0 + (KC) * 64];                                            \
    half8 z1 = zlb[o1 + (KC) * 64];                                            \
    half8 z2 = zlb[o2 + (KC) * 64];                                            \
    half8 z3 = zlb[o3 + (KC) * 64];                                            \
    cz0 = MFMA(z0, bf, cz0); cz1 = MFMA(z1, bf, cz1);                          \
    cz2 = MFMA(z2, bf, cz2); cz3 = MFMA(z3, bf, cz3);                          \
    cn0 = MFMA(N0, bf, cn0); cn1 = MFMA(N1, bf, cn1);                          \
    cn2 = MFMA(N2, bf, cn2); cn3 = MFMA(N3, bf, cn3); }

#define NL(P, N0, N1, N2, N3)                                                  \
    N0 = nlb[o0 + (P) * 64]; N1 = nlb[o1 + (P) * 64];                          \
    N2 = nlb[o2 + (P) * 64]; N3 = nlb[o3 + (P) * 64];

// Kernel 2: delta-GRU via MFMA. 256 threads (4 waves, 1/SIMD), one block per
// batch. Rounds 0-10 proved the fdot2 path is VALU-ISSUE-bound (~1536
// cyc/step at ~4cyc/fdot2; removing the entire spill stream in round 10
// changed nothing). The mac moves to the matrix pipe: 96 MFMA/wave/step
// (~480 cyc) vs 384 fdot2-wave-inst (~1536). B = dh broadcast to all 16
// cols -> every lane holds a full copy of each 16-row result -> extraction
// is pure cndmask. k-layout errors cancel (same pi for A and B); only the
// verified C/D layout (col=lane&15, row=(lane>>4)*4+reg) is load-bearing.
// Tiers: r-gate fragments register-resident (128 VGPR; cap at 256 thr =
// 65536/256 = 256), z in LDS (128 KB fragment-packed), n streamed from L2
// (128 KB/step, double-buffered groups threaded through the z-phase).
__global__ __launch_bounds__(256) void k_gru(
        const float* __restrict__ feats, const float* __restrict__ Wx,
        const float* __restrict__ Wh, const float* __restrict__ Wo,
        const _Float16* __restrict__ zp, const _Float16* __restrict__ np,
        float* __restrict__ out) {
    extern __shared__ __align__(16) char smem[];
    _Float16* z_lds = (_Float16*)smem;                          // 128 KB
    float*    s_wx  = (float*)(smem + 131072);                  // 20 KB [256*20]
    _Float16* s_dhh = (_Float16*)(smem + 131072 + 20480);       // [2][256]
    float*    s_dx  = (float*)(smem + 131072 + 20480 + 1024);   // [2][8]

    const int tid  = threadIdx.x;
    const int w    = tid >> 6;
    const int lane = tid & 63;
    const int a_   = (lane >> 4) & 3;
    const bool c1  = lane & 1, c2 = lane & 2, b1t = lane & 4, b2t = lane & 8;
    const int rowR = 64 * w + 16 * ((lane >> 2) & 3) + 4 * a_ + (lane & 3);
    const int b    = blockIdx.x;
    const float* fb = feats + (size_t)b * TT * FIN;
    float* outb = out + (size_t)b * TT * 2;

    // stage z fragments into LDS (layout preserved from k_pack)
    for (int i = tid; i < 8192; i += 256)
        ((float4*)z_lds)[i] = ((const float4*)zp)[i];
    // stage Wx into LDS, [row][20] (stride 80 B, slots 18..19 unused)
    for (int i = tid; i < 256 * 18; i += 256) {
        int r = i / 18, gf = i - r * 18;
        int g = gf / 6, f = gf - g * 6;
        s_wx[r * 20 + gf] = Wx[((size_t)g * HH + r) * FIN + f];
    }
    if (tid < 4) s_dx[(tid >> 1) * 8 + 6 + (tid & 1)] = 0.0f;   // zero pads

    // resident r-gate A-fragments: 4 tiles (rows 64w..64w+63) x 8 k-chunks
    half8 ar[4][8];
#pragma unroll
    for (int ti = 0; ti < 4; ti++) {
#pragma unroll
        for (int kc = 0; kc < 8; kc++) {
            const float* q = Wh + ((size_t)(16 * (4 * w + ti) + (lane & 15))) * HH
                           + 32 * kc + a_ * 8;
            float4 u = *(const float4*)q;
            float4 v = *(const float4*)(q + 4);
            half8 tt;
            tt[0] = (_Float16)u.x; tt[1] = (_Float16)u.y;
            tt[2] = (_Float16)u.z; tt[3] = (_Float16)u.w;
            tt[4] = (_Float16)v.x; tt[5] = (_Float16)v.y;
            tt[6] = (_Float16)v.z; tt[7] = (_Float16)v.w;
            ar[ti][kc] = tt;
        }
    }
    const float wo0 = Wo[rowR], wo1 = Wo[HH + rowR];

    const half8* zlb = (const half8*)z_lds;
    const half8* nlb = (const half8*)np;
    const int o0 = (4 * w + 0) * 512 + lane;
    const int o1 = (4 * w + 1) * 512 + lane;
    const int o2 = (4 * w + 2) * 512 + lane;
    const int o3 = (4 * w + 3) * 512 + lane;

    float h = 0.0f, hp = 0.0f, dmr = 0.0f, dmz = 0.0f, dmn = 0.0f, dmnh = 0.0f;
    float xp = 0.0f, curf = 0.0f, curfN = 0.0f;
    if (tid < FIN) curf = fb[tid];

    __syncthreads();

    for (int t = 0; t < TT; t++) {
        const int tb = t & 1;
        const _Float16* dhb = s_dhh + tb * HH;

        // ---- phase A ----
        {
            float dh = h - hp;
            bool keep = fabsf(dh) >= TH;
            s_dhh[tb * HH + rowR] = (_Float16)(keep ? dh : 0.0f);
            if (keep) hp = h;
        }
        if (tid < FIN) {
            float dx = curf - xp;
            bool keep = fabsf(dx) >= TH;
            s_dx[tb * 8 + tid] = keep ? dx : 0.0f;
            if (keep) xp = curf;
            // early prefetch of next step's feature (consumed next iter)
            if (t + 1 < TT) curfN = fb[(size_t)(t + 1) * FIN + tid];
        }
        // prefetch n k-groups 0,1 (step-invariant data; no barrier dep)
        half8 nA0, nA1, nA2, nA3, nB0, nB1, nB2, nB3;
        NL(0, nA0, nA1, nA2, nA3)
        NL(1, nB0, nB1, nB2, nB3)

        __syncthreads();

        // ---- mac_x (fp32 exact, per owned row, weights from LDS) ----
        float mxr, mxz, mxn;
        {
            const float4 da = *(const float4*)(s_dx + tb * 8);
            const float4 db = *(const float4*)(s_dx + tb * 8 + 4);
            const float4 x0 = *(const float4*)(s_wx + rowR * 20);
            const float4 x1 = *(const float4*)(s_wx + rowR * 20 + 4);
            const float4 x2 = *(const float4*)(s_wx + rowR * 20 + 8);
            const float4 x3 = *(const float4*)(s_wx + rowR * 20 + 12);
            const float4 x4 = *(const float4*)(s_wx + rowR * 20 + 16);
            mxr = fmaf(da.x, x0.x, fmaf(da.y, x0.y, fmaf(da.z, x0.z,
                  fmaf(da.w, x0.w, fmaf(db.x, x1.x, db.y * x1.y)))));
            mxz = fmaf(da.x, x1.z, fmaf(da.y, x1.w, fmaf(da.z, x2.x,
                  fmaf(da.w, x2.y, fmaf(db.x, x2.z, db.y * x2.w)))));
            mxn = fmaf(da.x, x3.x, fmaf(da.y, x3.y, fmaf(da.z, x3.z,
                  fmaf(da.w, x3.w, fmaf(db.x, x4.x, db.y * x4.y)))));
        }

        // ---- r-gate: resident fragments ----
        f4 cr0 = {0.f,0.f,0.f,0.f}, cr1 = {0.f,0.f,0.f,0.f};
        f4 cr2 = {0.f,0.f,0.f,0.f}, cr3 = {0.f,0.f,0.f,0.f};
        RS(0) RS(1) RS(2) RS(3) RS(4) RS(5) RS(6) RS(7)
        float arv;
        EXTRACT(cr0, cr1, cr2, cr3, arv)

        // ---- z (LDS) + n (L2 stream, 2 groups in flight) ----
        f4 cz0 = {0.f,0.f,0.f,0.f}, cz1 = {0.f,0.f,0.f,0.f};
        f4 cz2 = {0.f,0.f,0.f,0.f}, cz3 = {0.f,0.f,0.f,0.f};
        f4 cn0 = {0.f,0.f,0.f,0.f}, cn1 = {0.f,0.f,0.f,0.f};
        f4 cn2 = {0.f,0.f,0.f,0.f}, cn3 = {0.f,0.f,0.f,0.f};
        ZN(0, nA0, nA1, nA2, nA3)  NL(2, nA0, nA1, nA2, nA3)
        ZN(1, nB0, nB1, nB2, nB3)  NL(3, nB0, nB1, nB2, nB3)
        ZN(2, nA0, nA1, nA2, nA3)  NL(4, nA0, nA1, nA2, nA3)
        ZN(3, nB0, nB1, nB2, nB3)  NL(5, nB0, nB1, nB2, nB3)
        ZN(4, nA0, nA1, nA2, nA3)  NL(6, nA0, nA1, nA2, nA3)
        ZN(5, nB0, nB1, nB2, nB3)  NL(7, nB0, nB1, nB2, nB3)
        ZN(6, nA0, nA1, nA2, nA3)
        ZN(7, nB0, nB1, nB2, nB3)
        float azv, anv;
        EXTRACT(cz0, cz1, cz2, cz3, azv)
        EXTRACT(cn0, cn1, cn2, cn3, anv)

        dmr += mxr + arv;
        dmz += mxz + azv;
        dmn += mxn;          // x-part of n
        dmnh += anv;         // h-part of n

        // ---- phase C ----
        {
            float r = sigm(dmr);
            float z = sigm(dmz);
            float nn = tanhf_fast(dmn + r * dmnh);
            h = (1.0f - z) * nn + z * h;
        }

        // ---- output: 1 row/thread; reduce 64 rows/wave per channel ----
        {
            float p0 = h * wo0, p1 = h * wo1;
            p0 += __shfl_xor(p0, 16, 64); p0 += __shfl_xor(p0, 32, 64);
            p0 = dpp_row_sum16(p0);
            p1 += __shfl_xor(p1, 16, 64); p1 += __shfl_xor(p1, 32, 64);
            p1 = dpp_row_sum16(p1);
            if (lane == 15) atomicAdd(&outb[2 * t + 0], p0);
            if (lane == 31) atomicAdd(&outb[2 * t + 1], p1);
        }

        curf = curfN;
    }
}

extern "C" void kernel_launch(void* const* d_in, const int* in_sizes, int n_in,
                              void* d_out, int out_size, void* d_ws, size_t ws_size,
                              hipStream_t stream) {
    const float* x   = (const float*)d_in[0];
    const float* Wx  = (const float*)d_in[1];
    const float* Wh  = (const float*)d_in[2];
    const float* Wo  = (const float*)d_in[3];
    const float* Wc1 = (const float*)d_in[4];
    const float* Wc2 = (const float*)d_in[5];
    float* out = (float*)d_out;
    float* feats = (float*)d_ws;                                   // 3.07 MB
    _Float16* zp = (_Float16*)((char*)d_ws + 3145728);             // 128 KB
    _Float16* np = (_Float16*)((char*)d_ws + 3145728 + 131072);    // 128 KB

    k_prep<<<(BB * TT + 255) / 256, 256, 0, stream>>>(x, Wc1, Wc2, feats, out);
    k_pack<<<64, 256, 0, stream>>>(Wh, zp, np);
    hipFuncSetAttribute(reinterpret_cast<const void*>(k_gru),
                        hipFuncAttributeMaxDynamicSharedMemorySize, 152640);
    k_gru<<<BB, 256, 152640, stream>>>(feats, Wx, Wh, Wo, zp, np, out);
}

// Round 12
// 6666.713 us; speedup vs baseline: 1.3483x; 1.3483x over previous
//
#include <hip/hip_runtime.h>
#include <math.h>

#define HH 256
#define FIN 6
#define TT 4096
#define BB 32
#define TH 0.05f

typedef _Float16 half8 __attribute__((ext_vector_type(8)));
typedef float f4 __attribute__((ext_vector_type(4)));

__device__ __forceinline__ float hswish(float v) {
    float c = fminf(fmaxf(v + 3.0f, 0.0f), 6.0f);
    return v * c * (1.0f / 6.0f);
}
__device__ __forceinline__ float fexp2(float x) { return __builtin_amdgcn_exp2f(x); }
__device__ __forceinline__ float frcp(float x)  { return __builtin_amdgcn_rcpf(x); }
__device__ __forceinline__ float sigm(float x)  { return frcp(1.0f + fexp2(-1.44269504f * x)); }
__device__ __forceinline__ float tanhf_fast(float x) {
    float ax = fabsf(x);
    float e = fexp2(2.88539008f * ax);
    float t = 1.0f - 2.0f * frcp(e + 1.0f);
    return copysignf(t, x);
}

// DPP row_shr sum over 16 lanes (VALU pipe); sum lands in lane 15 of each row.
__device__ __forceinline__ float dpp_row_sum16(float p) {
    int x = __float_as_int(p);
    p += __int_as_float(__builtin_amdgcn_update_dpp(0, x, 0x118, 0xF, 0xF, true));
    x = __float_as_int(p);
    p += __int_as_float(__builtin_amdgcn_update_dpp(0, x, 0x114, 0xF, 0xF, true));
    x = __float_as_int(p);
    p += __int_as_float(__builtin_amdgcn_update_dpp(0, x, 0x112, 0xF, 0xF, true));
    x = __float_as_int(p);
    p += __int_as_float(__builtin_amdgcn_update_dpp(0, x, 0x111, 0xF, 0xF, true));
    return p;
}

// Kernel 1: feats (B,T,6) into ws, conv skip path into d_out.
__global__ __launch_bounds__(256) void k_prep(
        const float* __restrict__ x, const float* __restrict__ Wc1,
        const float* __restrict__ Wc2, float* __restrict__ feats,
        float* __restrict__ out) {
    int idx = blockIdx.x * 256 + threadIdx.x;   // b*T + t
    if (idx >= BB * TT) return;
    int b = idx >> 12;
    int t = idx & (TT - 1);
    const float* xb = x + (size_t)b * TT * 2;
    float i0 = xb[t * 2 + 0], q0 = xb[t * 2 + 1];
    float ip = (t > 0) ? xb[(t - 1) * 2 + 0] : 0.0f;
    float qp = (t > 0) ? xb[(t - 1) * 2 + 1] : 0.0f;
    float amp2 = i0 * i0 + q0 * q0;
    float amp  = sqrtf(fmaxf(amp2, 1e-12f));
    float amp3 = amp * amp2;
    float* f = feats + (size_t)idx * 6;
    f[0] = i0; f[1] = q0; f[2] = amp; f[3] = amp3; f[4] = ip; f[5] = qp;

    float c1[3];
#pragma unroll
    for (int m = 0; m < 3; m++) {
        float acc = 0.0f;
#pragma unroll
        for (int k = 0; k < 3; k++) {
            int tt = t + (k - 1) * 16;
            if (tt >= 0 && tt < TT) {
                acc += Wc1[m * 6 + 0 * 3 + k] * xb[tt * 2 + 0];
                acc += Wc1[m * 6 + 1 * 3 + k] * xb[tt * 2 + 1];
            }
        }
        c1[m] = hswish(acc);
    }
#pragma unroll
    for (int o = 0; o < 2; o++) {
        float acc = Wc2[o * 3 + 0] * c1[0] + Wc2[o * 3 + 1] * c1[1] + Wc2[o * 3 + 2] * c1[2];
        out[(size_t)idx * 2 + o] = hswish(acc);
    }
}

// Kernel 1b: pack the n-gate (gate 2) as fp16 MFMA A-fragments.
// fid = (rt*8 + kc)*64 + lane holds Wh[2][16*rt + (lane&15)][32*kc + a_*8 + j].
// This exact layout passed verification in round 11.
__global__ __launch_bounds__(256) void k_pack(
        const float* __restrict__ Wh, _Float16* __restrict__ np) {
    int id = blockIdx.x * 256 + threadIdx.x;     // 0..8191
    if (id >= 8192) return;
    int rt  = id >> 9;
    int kc  = (id >> 6) & 7;
    int ln  = id & 63;
    const float* s = Wh + ((size_t)(2 * HH + 16 * rt + (ln & 15))) * HH
                   + 32 * kc + ((ln >> 4) & 3) * 8;
    _Float16* d = np + (size_t)id * 8;
    float4 u = *(const float4*)s;
    float4 v = *(const float4*)(s + 4);
    d[0] = (_Float16)u.x; d[1] = (_Float16)u.y; d[2] = (_Float16)u.z; d[3] = (_Float16)u.w;
    d[4] = (_Float16)v.x; d[5] = (_Float16)v.y; d[6] = (_Float16)v.z; d[7] = (_Float16)v.w;
}

#define MFMA(A, B, C) __builtin_amdgcn_mfma_f32_16x16x32_f16((A), (B), (C), 0, 0, 0)

// reg-select by lane bits 0,1; tile-select by lane bit 2 (same pattern as the
// round-11-verified 4-tile extract, restricted to 2 tiles).
#define EXTRACT2(C0, C1, DST) {                                                \
    float e0_ = c2 ? (c1 ? C0[3] : C0[2]) : (c1 ? C0[1] : C0[0]);              \
    float e1_ = c2 ? (c1 ? C1[3] : C1[2]) : (c1 ? C1[1] : C1[0]);              \
    DST = tsel ? e1_ : e0_; }

// Kernel 2: delta-GRU via MFMA, 512 threads (8 waves, 2/SIMD). Round 11
// proved the MFMA math correct but ran 1 wave/SIMD with a per-step 128 KB
// L2 stream: MfmaUtil 3.6 + VALUBusy 3.2 (both idle) = latency-exposed.
// This round: wave owns 2 row-tiles (32 rows); r+z gate fragments
// REGISTER-resident (64 VGPR, fits the 128 cap at 512 thr); n-gate
// fragments in LDS (128 KB, round-11 layout); Wx transposed in LDS
// ([g*6+f][row] -> conflict-free rowR reads, kills the 11.5M stride-20
// conflicts). ZERO per-step global traffic; 1 barrier/step.
__global__ __launch_bounds__(512) void k_gru(
        const float* __restrict__ feats, const float* __restrict__ Wx,
        const float* __restrict__ Wh, const float* __restrict__ Wo,
        const _Float16* __restrict__ np, float* __restrict__ out) {
    extern __shared__ __align__(16) char smem[];
    _Float16* n_lds = (_Float16*)smem;                           // 128 KB
    float*    s_wxT = (float*)(smem + 131072);                   // 18 KB
    _Float16* s_dhh = (_Float16*)(smem + 131072 + 18432);        // [2][256]
    float*    s_dx  = (float*)(smem + 131072 + 18432 + 1024);    // [2][8]

    const int tid  = threadIdx.x;
    const int w    = tid >> 6;          // wave 0..7 -> row-tiles 2w, 2w+1
    const int lane = tid & 63;
    const int a_   = (lane >> 4) & 3;
    const bool c1  = lane & 1, c2 = lane & 2, tsel = lane & 4;
    const bool owner = !(lane & 8);     // 32 owner lanes cover the 32 rows
    const int rowR = 32 * w + 16 * ((lane >> 2) & 1) + 4 * a_ + (lane & 3);
    const int b    = blockIdx.x;
    const float* fb = feats + (size_t)b * TT * FIN;
    float* outb = out + (size_t)b * TT * 2;

    // stage n fragments into LDS (layout preserved from k_pack)
    for (int i = tid; i < 8192; i += 512)
        ((float4*)n_lds)[i] = ((const float4*)np)[i];
    // stage Wx transposed: s_wxT[(g*6+f)*256 + row]
    for (int i = tid; i < 18 * 256; i += 512) {
        int gf = i >> 8, r = i & 255;
        s_wxT[i] = Wx[((size_t)(gf / 6) * HH + r) * FIN + (gf % 6)];
    }
    if (tid < 4) s_dx[(tid >> 1) * 8 + 6 + (tid & 1)] = 0.0f;

    // register-resident r and z gate A-fragments: 2 tiles x 8 k-chunks each
    half8 wrg[2][8], wzg[2][8];
#pragma unroll
    for (int ti = 0; ti < 2; ti++) {
#pragma unroll
        for (int kc = 0; kc < 8; kc++) {
            const int r16 = 16 * (2 * w + ti) + (lane & 15);
            const float* q0 = Wh + ((size_t)(0 * HH + r16)) * HH + 32 * kc + a_ * 8;
            const float* q1 = Wh + ((size_t)(1 * HH + r16)) * HH + 32 * kc + a_ * 8;
            float4 u = *(const float4*)q0;
            float4 v = *(const float4*)(q0 + 4);
            half8 t0;
            t0[0] = (_Float16)u.x; t0[1] = (_Float16)u.y;
            t0[2] = (_Float16)u.z; t0[3] = (_Float16)u.w;
            t0[4] = (_Float16)v.x; t0[5] = (_Float16)v.y;
            t0[6] = (_Float16)v.z; t0[7] = (_Float16)v.w;
            wrg[ti][kc] = t0;
            u = *(const float4*)q1;
            v = *(const float4*)(q1 + 4);
            half8 t1;
            t1[0] = (_Float16)u.x; t1[1] = (_Float16)u.y;
            t1[2] = (_Float16)u.z; t1[3] = (_Float16)u.w;
            t1[4] = (_Float16)v.x; t1[5] = (_Float16)v.y;
            t1[6] = (_Float16)v.z; t1[7] = (_Float16)v.w;
            wzg[ti][kc] = t1;
        }
    }
    const float wo0 = Wo[rowR], wo1 = Wo[HH + rowR];
    const half8* nlb = (const half8*)n_lds;

    float h = 0.0f, hp = 0.0f, dmr = 0.0f, dmz = 0.0f, dmn = 0.0f, dmnh = 0.0f;
    float xp = 0.0f, curf = 0.0f, curfN = 0.0f;
    if (tid < FIN) curf = fb[tid];

    __syncthreads();

    for (int t = 0; t < TT; t++) {
        const int tb = t & 1;
        _Float16* dhw = s_dhh + tb * HH;

        // ---- phase A ----
        {
            float dh = h - hp;
            bool keep = fabsf(dh) >= TH;
            if (owner) dhw[rowR] = (_Float16)(keep ? dh : 0.0f);
            if (keep) hp = h;
        }
        if (tid < FIN) {
            float dx = curf - xp;
            bool keep = fabsf(dx) >= TH;
            s_dx[tb * 8 + tid] = keep ? dx : 0.0f;
            if (keep) xp = curf;
            if (t + 1 < TT) curfN = fb[(size_t)(t + 1) * FIN + tid];
        }
        __syncthreads();

        // ---- mac_x (fp32 exact; transposed Wx reads are conflict-free) ----
        float mxr, mxz, mxn;
        {
            float d0 = s_dx[tb * 8 + 0], d1 = s_dx[tb * 8 + 1], d2 = s_dx[tb * 8 + 2];
            float d3 = s_dx[tb * 8 + 3], d4 = s_dx[tb * 8 + 4], d5 = s_dx[tb * 8 + 5];
            const float* W0 = s_wxT + rowR;
            const float* W1 = s_wxT + 6 * 256 + rowR;
            const float* W2 = s_wxT + 12 * 256 + rowR;
            mxr = fmaf(d0, W0[0], fmaf(d1, W0[256], fmaf(d2, W0[512],
                  fmaf(d3, W0[768], fmaf(d4, W0[1024], d5 * W0[1280])))));
            mxz = fmaf(d0, W1[0], fmaf(d1, W1[256], fmaf(d2, W1[512],
                  fmaf(d3, W1[768], fmaf(d4, W1[1024], d5 * W1[1280])))));
            mxn = fmaf(d0, W2[0], fmaf(d1, W2[256], fmaf(d2, W2[512],
                  fmaf(d3, W2[768], fmaf(d4, W2[1024], d5 * W2[1280])))));
        }

        // ---- 3 gates x 2 tiles x 8 k-chunks: 48 MFMA, 6 indep chains ----
        f4 cr0 = {0.f,0.f,0.f,0.f}, cr1 = {0.f,0.f,0.f,0.f};
        f4 cz0 = {0.f,0.f,0.f,0.f}, cz1 = {0.f,0.f,0.f,0.f};
        f4 cn0 = {0.f,0.f,0.f,0.f}, cn1 = {0.f,0.f,0.f,0.f};
#define STEPK(KC) {                                                            \
        half8 bf = *(const half8*)(dhw + 32 * (KC) + a_ * 8);                  \
        half8 n0 = nlb[((2 * w + 0) * 8 + (KC)) * 64 + lane];                  \
        half8 n1 = nlb[((2 * w + 1) * 8 + (KC)) * 64 + lane];                  \
        cr0 = MFMA(wrg[0][KC], bf, cr0); cr1 = MFMA(wrg[1][KC], bf, cr1);      \
        cz0 = MFMA(wzg[0][KC], bf, cz0); cz1 = MFMA(wzg[1][KC], bf, cz1);      \
        cn0 = MFMA(n0, bf, cn0);         cn1 = MFMA(n1, bf, cn1); }
        STEPK(0) STEPK(1) STEPK(2) STEPK(3)
        STEPK(4) STEPK(5) STEPK(6) STEPK(7)
#undef STEPK
        float arv, azv, anv;
        EXTRACT2(cr0, cr1, arv)
        EXTRACT2(cz0, cz1, azv)
        EXTRACT2(cn0, cn1, anv)

        dmr += mxr + arv;
        dmz += mxz + azv;
        dmn += mxn;          // x-part of n
        dmnh += anv;         // h-part of n

        // ---- phase C ----
        {
            float r = sigm(dmr);
            float z = sigm(dmz);
            float nn = tanhf_fast(dmn + r * dmnh);
            h = (1.0f - z) * nn + z * h;
        }

        // ---- output: owner lanes contribute once per row; wave-reduce ----
        {
            float p0 = owner ? h * wo0 : 0.0f;
            float p1 = owner ? h * wo1 : 0.0f;
            p0 += __shfl_xor(p0, 16, 64); p0 += __shfl_xor(p0, 32, 64);
            p0 = dpp_row_sum16(p0);
            p1 += __shfl_xor(p1, 16, 64); p1 += __shfl_xor(p1, 32, 64);
            p1 = dpp_row_sum16(p1);
            if (lane == 15) atomicAdd(&outb[2 * t + 0], p0);
            if (lane == 31) atomicAdd(&outb[2 * t + 1], p1);
        }

        curf = curfN;
    }
}

extern "C" void kernel_launch(void* const* d_in, const int* in_sizes, int n_in,
                              void* d_out, int out_size, void* d_ws, size_t ws_size,
                              hipStream_t stream) {
    const float* x   = (const float*)d_in[0];
    const float* Wx  = (const float*)d_in[1];
    const float* Wh  = (const float*)d_in[2];
    const float* Wo  = (const float*)d_in[3];
    const float* Wc1 = (const float*)d_in[4];
    const float* Wc2 = (const float*)d_in[5];
    float* out = (float*)d_out;
    float* feats = (float*)d_ws;                                   // 3.07 MB
    _Float16* np = (_Float16*)((char*)d_ws + 3145728);             // 128 KB

    k_prep<<<(BB * TT + 255) / 256, 256, 0, stream>>>(x, Wc1, Wc2, feats, out);
    k_pack<<<32, 256, 0, stream>>>(Wh, np);
    hipFuncSetAttribute(reinterpret_cast<const void*>(k_gru),
                        hipFuncAttributeMaxDynamicSharedMemorySize, 150592);
    k_gru<<<BB, 512, 150592, stream>>>(feats, Wx, Wh, Wo, np, out);
}